// Round 4
// baseline (1631.463 us; speedup 1.0000x reference)
//
#include <hip/hip_runtime.h>
#include <hip/hip_bf16.h>

#define IN_C 128
#define HEADS 4
#define HID 32
#define OUT_C 64
#define NEG_SLOPE 0.2f

static __device__ __forceinline__ float bf2f(__hip_bfloat16 b) { return __bfloat162float(b); }

static __device__ __forceinline__ int clampIdx(int i, int n) {
    return ((unsigned)i < (unsigned)n) ? i : 0;  // valid inputs unaffected
}

// Dual-path input load: fp32 (reference dtype; expected) or bf16 (env-converted).
// isF==1 -> buffer is fp32. Probed at runtime by k0_probe.
static __device__ __forceinline__ float ldIn(const void* p, size_t i, int isF) {
    return isF ? ((const float*)p)[i] : bf2f(((const __hip_bfloat16*)p)[i]);
}

// Dual-path edge load: edge_index may be int64 (reference dtype) or int32 on device.
static __device__ __forceinline__ int ldSrc(const int* ei, int e, int E, int i64) {
    return i64 ? ei[2 * e] : ei[e];
}
static __device__ __forceinline__ int ldDst(const int* ei, int e, int E, int i64) {
    return i64 ? ei[2 * (E + e)] : ei[E + e];
}

// ---------------- probes ----------------
// flags[0] != 0  -> inputs are fp32 (bf16 view of fp32 bits has wild exponents)
// flags[1] == 0  -> edge_index is int64 (all odd dwords zero); !=0 -> int32
__global__ void k0_probe(const void* x, const int* ei, int* flags) {
    int t = threadIdx.x;  // 512 threads
    float v = bf2f(((const __hip_bfloat16*)x)[t]);
    if (!(fabsf(v) <= 1e10f)) atomicOr(&flags[0], 1);  // catches huge and NaN
    if (t < 256) {
        if (ei[2 * t + 1] != 0) atomicOr(&flags[1], 1);
    }
}

// ---------------- CSR build (int atomics only) ----------------
__global__ void k_count(const int* __restrict__ ei, const int* __restrict__ flags,
                        int* __restrict__ cnt, int E, int N) {
    int e = blockIdx.x * 256 + threadIdx.x;
    if (e >= E) return;
    int i64 = (flags[1] == 0);
    int dst = clampIdx(ldDst(ei, e, E, i64), N);
    atomicAdd(&cnt[dst], 1);
}

// single-block scan: cnt -> exclusive prefix; writes off[0..N] and resets cnt to running cursors
__global__ void k_scan(int* __restrict__ cnt_pos, int* __restrict__ off, int N) {
    __shared__ int buf[1024];
    __shared__ int sbase;
    int t = threadIdx.x;
    if (t == 0) sbase = 0;
    __syncthreads();
    for (int start = 0; start < N; start += 1024) {
        int i = start + t;
        int v = (i < N) ? cnt_pos[i] : 0;
        buf[t] = v;
        __syncthreads();
        for (int o = 1; o < 1024; o <<= 1) {
            int tv = (t >= o) ? buf[t - o] : 0;
            __syncthreads();
            buf[t] += tv;
            __syncthreads();
        }
        int incl = buf[t];
        int total = buf[1023];
        int b = sbase;
        __syncthreads();
        if (i < N) {
            int ex = b + incl - v;
            off[i] = ex;
            cnt_pos[i] = ex;
        }
        if (t == 0) sbase = b + total;
        __syncthreads();
    }
    if (t == 0) off[N] = sbase;
}

__global__ void k_fill(const int* __restrict__ ei, const int* __restrict__ flags,
                       int* __restrict__ pos, int* __restrict__ srcs, int E, int N) {
    int e = blockIdx.x * 256 + threadIdx.x;
    if (e >= E) return;
    int i64 = (flags[1] == 0);
    int src = clampIdx(ldSrc(ei, e, E, i64), N);
    int dst = clampIdx(ldDst(ei, e, E, i64), N);
    int p = atomicAdd(&pos[dst], 1);
    if (p >= 0 && p < E) srcs[p] = src;
}

// ---------------- layer 1 GEMM + logits ----------------
// h1[N,128] bf16 = x @ W1; al_s/al_d[N,4] fp32. block=128 (2 waves, 1 node/wave).
__global__ void k1_gemm1(const void* __restrict__ x, const void* __restrict__ W1,
                         const void* __restrict__ a_s, const void* __restrict__ a_d,
                         const int* __restrict__ flags,
                         __hip_bfloat16* __restrict__ h1,
                         float* __restrict__ al_s, float* __restrict__ al_d, int N) {
    int fF = flags[0];
    int t = threadIdx.x;
    int nl = t >> 6, tt = t & 63;
    int n = blockIdx.x * 2 + nl;
    __shared__ float xs[2][128];
    {
        int nn = blockIdx.x * 2 + (t >> 6);
        int kk = (t & 63) * 2;
        float lo = 0.f, hi = 0.f;
        if (nn < N) {
            lo = ldIn(x, (size_t)nn * 128 + kk, fF);
            hi = ldIn(x, (size_t)nn * 128 + kk + 1, fF);
        }
        xs[t >> 6][kk] = lo;
        xs[t >> 6][kk + 1] = hi;
    }
    __syncthreads();
    float acc0 = 0.f, acc1 = 0.f;
    #pragma unroll 8
    for (int k = 0; k < 128; ++k) {
        float xv = xs[nl][k];
        acc0 = fmaf(xv, ldIn(W1, (size_t)k * 128 + 2 * tt, fF), acc0);
        acc1 = fmaf(xv, ldIn(W1, (size_t)k * 128 + 2 * tt + 1, fF), acc1);
    }
    if (n < N) {
        __hip_bfloat162 pk;
        pk.x = __float2bfloat16(acc0);
        pk.y = __float2bfloat16(acc1);
        ((__hip_bfloat162*)h1)[(size_t)n * 64 + tt] = pk;
    }
    float ps = acc0 * ldIn(a_s, 2 * tt, fF) + acc1 * ldIn(a_s, 2 * tt + 1, fF);
    float pd = acc0 * ldIn(a_d, 2 * tt, fF) + acc1 * ldIn(a_d, 2 * tt + 1, fF);
    #pragma unroll
    for (int o = 8; o > 0; o >>= 1) {
        ps += __shfl_down(ps, o, 16);
        pd += __shfl_down(pd, o, 16);
    }
    if ((tt & 15) == 0 && n < N) {
        int h = tt >> 4;
        al_s[n * 4 + h] = ps;
        al_d[n * 4 + h] = pd;
    }
}

// ---------------- fused layer-1 aggregation + ELU + GEMM2 + layer-2 logits ----------------
// one block (128 thr) per dst node; thread t owns channel t of the 128-dim aggregate.
__global__ void k2_fused1(const int* __restrict__ off, const int* __restrict__ srcs,
                          const __hip_bfloat16* __restrict__ h1,
                          const float* __restrict__ al_s, const float* __restrict__ al_d,
                          const void* __restrict__ b1, const void* __restrict__ W2,
                          const void* __restrict__ a_s2, const void* __restrict__ a_d2,
                          const int* __restrict__ flags,
                          __hip_bfloat16* __restrict__ h2,
                          float* __restrict__ al_s2, float* __restrict__ al_d2, int N) {
    int d = blockIdx.x;
    int t = threadIdx.x;           // 0..127
    int fF = flags[0];
    int s0 = off[d], s1e = off[d + 1];
    int h = t >> 5;                // head of channel t
    float ald = al_d[d * 4 + h];
    float acc = 0.f, ssum = 0.f;   // ssum identical across the 32 threads of a head
    for (int j = s0; j < s1e; ++j) {
        int src = srcs[j];
        float v = al_s[src * 4 + h] + ald;
        v = v >= 0.f ? v : NEG_SLOPE * v;
        float e = __expf(fminf(v, 30.f));   // clamp: no inf possible
        ssum += e;
        acc += e * bf2f(h1[(size_t)src * 128 + t]);
    }
    float o1 = acc / (ssum + 1e-16f);       // deg==0 -> 0/1e-16 = 0, matches ref
    float tlv = o1 + ldIn(b1, t, fF);
    tlv = tlv > 0.f ? tlv : (__expf(tlv) - 1.f);  // elu (arg <= 0 -> exp <= 1)
    __shared__ float tl[128];
    tl[t] = tlv;
    __syncthreads();
    if (t < 64) {                  // wave 0 computes the 64-dim GEMM2 output
        float a2 = 0.f;
        #pragma unroll 8
        for (int k = 0; k < 128; ++k)
            a2 = fmaf(tl[k], ldIn(W2, (size_t)k * 64 + t, fF), a2);
        h2[(size_t)d * 64 + t] = __float2bfloat16(a2);
        float ps = a2 * ldIn(a_s2, t, fF);
        float pd = a2 * ldIn(a_d2, t, fF);
        #pragma unroll
        for (int o = 32; o > 0; o >>= 1) {
            ps += __shfl_down(ps, o, 64);
            pd += __shfl_down(pd, o, 64);
        }
        if (t == 0) { al_s2[d] = ps; al_d2[d] = pd; }
    }
}

// ---------------- fused layer-2 aggregation + bias -> FP32 output ----------------
__global__ void k3_fused2(const int* __restrict__ off, const int* __restrict__ srcs,
                          const __hip_bfloat16* __restrict__ h2,
                          const float* __restrict__ al_s2, const float* __restrict__ al_d2,
                          const void* __restrict__ b2, const int* __restrict__ flags,
                          float* __restrict__ out, int N) {
    int d = blockIdx.x;
    int t = threadIdx.x;           // 0..63
    int fF = flags[0];
    int s0 = off[d], s1e = off[d + 1];
    float ald = al_d2[d];
    float acc = 0.f, ssum = 0.f;
    for (int j = s0; j < s1e; ++j) {
        int src = srcs[j];
        float v = al_s2[src] + ald;
        v = v >= 0.f ? v : NEG_SLOPE * v;
        float e = __expf(fminf(v, 30.f));
        ssum += e;
        acc += e * bf2f(h2[(size_t)src * 64 + t]);
    }
    out[(size_t)d * 64 + t] = acc / (ssum + 1e-16f) + ldIn(b2, t, fF);
}

// diagnostic: ws too small -> broadcast ws_size in MB so the bench absmax reports it
__global__ void k_report(float* out, int total, float code) {
    int i = blockIdx.x * 256 + threadIdx.x;
    if (i < total) out[i] = code;
}

extern "C" void kernel_launch(void* const* d_in, const int* in_sizes, int n_in,
                              void* d_out, int out_size, void* d_ws, size_t ws_size,
                              hipStream_t stream) {
    const void* x    = d_in[0];
    const int*  ei   = (const int*)d_in[1];
    const void* W1   = d_in[2];
    const void* a_s1 = d_in[3];
    const void* a_d1 = d_in[4];
    const void* b1   = d_in[5];
    const void* W2   = d_in[6];
    const void* a_s2 = d_in[7];
    const void* a_d2 = d_in[8];
    const void* b2   = d_in[9];
    const int N = in_sizes[0] / IN_C;
    const int E = in_sizes[1] / 2;

    // compact layout, ~49.7 MB total (round 3 proved ws_size >= this: report didn't fire)
    char* p = (char*)d_ws;
    int* flags   = (int*)p;                 p += 256;
    int* csr_off = (int*)p;                 p += ((size_t)(N + 1) * 4 + 255) / 256 * 256;
    int* csr_pos = (int*)p;                 p += ((size_t)N * 4 + 255) / 256 * 256;  // counts, then cursors
    int* csr_src = (int*)p;                 p += ((size_t)E * 4 + 255) / 256 * 256;
    float* al_s1 = (float*)p;               p += (size_t)N * 4 * 4;
    float* al_d1 = (float*)p;               p += (size_t)N * 4 * 4;
    float* al_s2 = (float*)p;               p += (size_t)N * 4;
    float* al_d2 = (float*)p;               p += (size_t)N * 4;
    __hip_bfloat16* h1 = (__hip_bfloat16*)p; p += (size_t)N * 128 * 2;
    __hip_bfloat16* h2 = (__hip_bfloat16*)p; p += (size_t)N * 64 * 2;
    size_t needed = (size_t)(p - (char*)d_ws);

    if (ws_size < needed) {
        k_report<<<(out_size + 255) / 256, 256, 0, stream>>>(
            (float*)d_out, out_size, (float)(ws_size >> 20));
        return;
    }

    hipMemsetAsync(flags, 0, 256, stream);
    hipMemsetAsync(csr_pos, 0, (size_t)N * 4, stream);

    k0_probe<<<1, 512, 0, stream>>>(x, ei, flags);
    k_count<<<(E + 255) / 256, 256, 0, stream>>>(ei, flags, csr_pos, E, N);
    k_scan<<<1, 1024, 0, stream>>>(csr_pos, csr_off, N);
    k_fill<<<(E + 255) / 256, 256, 0, stream>>>(ei, flags, csr_pos, csr_src, E, N);

    k1_gemm1<<<(N + 1) / 2, 128, 0, stream>>>(x, W1, a_s1, a_d1, flags, h1, al_s1, al_d1, N);
    k2_fused1<<<N, 128, 0, stream>>>(csr_off, csr_src, h1, al_s1, al_d1,
                                     b1, W2, a_s2, a_d2, flags, h2, al_s2, al_d2, N);
    k3_fused2<<<N, 64, 0, stream>>>(csr_off, csr_src, h2, al_s2, al_d2, b2, flags,
                                    (float*)d_out, N);
}

// Round 5
// 1557.144 us; speedup vs baseline: 1.0477x; 1.0477x over previous
//
#include <hip/hip_runtime.h>
#include <hip/hip_bf16.h>

#define IN_C 128
#define HEADS 4
#define HID 32
#define OUT_C 64
#define NEG_SLOPE 0.2f

static __device__ __forceinline__ float bf2f(__hip_bfloat16 b) { return __bfloat162float(b); }

static __device__ __forceinline__ int clampIdx(int i, int n) {
    return ((unsigned)i < (unsigned)n) ? i : 0;  // valid inputs unaffected
}

// Dual-path input load: fp32 (reference dtype; confirmed round 4) or bf16.
static __device__ __forceinline__ float ldIn(const void* p, size_t i, int isF) {
    return isF ? ((const float*)p)[i] : bf2f(((const __hip_bfloat16*)p)[i]);
}

// Dual-path edge load: int64 or int32, probed.
static __device__ __forceinline__ int ldSrc(const int* ei, int e, int E, int i64) {
    return i64 ? ei[2 * e] : ei[e];
}
static __device__ __forceinline__ int ldDst(const int* ei, int e, int E, int i64) {
    return i64 ? ei[2 * (E + e)] : ei[E + e];
}

// inclusive scan of v across 256 threads (4 waves)
static __device__ __forceinline__ int scan256_incl(int v, int t) {
    for (int o = 1; o < 64; o <<= 1) {
        int u = __shfl_up(v, o, 64);
        if ((t & 63) >= o) v += u;
    }
    __shared__ int wsum[4];
    if ((t & 63) == 63) wsum[t >> 6] = v;
    __syncthreads();
    int base = 0;
    #pragma unroll
    for (int i = 0; i < 4; ++i) base += (i < (t >> 6)) ? wsum[i] : 0;
    __syncthreads();
    return base + v;
}

// ---------------- probes ----------------
__global__ void k0_probe(const void* x, const int* ei, int* flags) {
    int t = threadIdx.x;  // 512
    float v = bf2f(((const __hip_bfloat16*)x)[t]);
    if (!(fabsf(v) <= 1e10f)) atomicOr(&flags[0], 1);  // fp32 detected
    if (t < 256) {
        if (ei[2 * t + 1] != 0) atomicOr(&flags[1], 1); // int32 detected
    }
}

// ---------------- CSR build ----------------
__global__ void k_count(const int* __restrict__ ei, const int* __restrict__ flags,
                        int* __restrict__ cnt, int E, int N) {
    int e = blockIdx.x * 256 + threadIdx.x;
    if (e >= E) return;
    int i64 = (flags[1] == 0);
    atomicAdd(&cnt[clampIdx(ldDst(ei, e, E, i64), N)], 1);
}

// phase A: per-2048-chunk sums
__global__ void k_scanA(const int* __restrict__ cnt, int* __restrict__ bsum, int N) {
    int t = threadIdx.x, blk = blockIdx.x;
    int s = 0;
    #pragma unroll
    for (int j = 0; j < 8; ++j) {
        int idx = blk * 2048 + j * 256 + t;
        s += (idx < N) ? cnt[idx] : 0;
    }
    #pragma unroll
    for (int o = 32; o > 0; o >>= 1) s += __shfl_down(s, o, 64);
    __shared__ int ws4[4];
    if ((t & 63) == 0) ws4[t >> 6] = s;
    __syncthreads();
    if (t == 0) bsum[blk] = ws4[0] + ws4[1] + ws4[2] + ws4[3];
}

// phase B: scan chunk sums (supports NB<=256), writes bases + off[N]
__global__ void k_scanB(const int* __restrict__ bsum, int* __restrict__ bbase,
                        int* __restrict__ off, int NB, int N) {
    int t = threadIdx.x;
    int v = (t < NB) ? bsum[t] : 0;
    int incl = scan256_incl(v, t);
    if (t < NB) bbase[t] = incl - v;
    if (t == 255) off[N] = incl;
}

// phase C: per-chunk exclusive scan + base; writes off[] and cursor pos[] (in place over counts)
__global__ void k_scanC(int* __restrict__ cnt_pos, int* __restrict__ off,
                        const int* __restrict__ bbase, int N) {
    int t = threadIdx.x, blk = blockIdx.x;
    int base_i = blk * 2048 + t * 8;
    int c[8], pre[8];
    #pragma unroll
    for (int j = 0; j < 8; ++j) c[j] = (base_i + j < N) ? cnt_pos[base_i + j] : 0;
    int s = 0;
    #pragma unroll
    for (int j = 0; j < 8; ++j) { pre[j] = s; s += c[j]; }
    int incl = scan256_incl(s, t);
    int gexcl = bbase[blk] + incl - s;
    #pragma unroll
    for (int j = 0; j < 8; ++j) {
        int i = base_i + j;
        if (i < N) {
            int v = gexcl + pre[j];
            off[i] = v;
            cnt_pos[i] = v;
        }
    }
}

__global__ void k_fill(const int* __restrict__ ei, const int* __restrict__ flags,
                       int* __restrict__ pos, int* __restrict__ srcs, int E, int N) {
    int e = blockIdx.x * 256 + threadIdx.x;
    if (e >= E) return;
    int i64 = (flags[1] == 0);
    int src = clampIdx(ldSrc(ei, e, E, i64), N);
    int dst = clampIdx(ldDst(ei, e, E, i64), N);
    int p = atomicAdd(&pos[dst], 1);
    if (p >= 0 && p < E) srcs[p] = src;
}

// ---------------- layer 1 GEMM + logits: weight-stationary LDS ----------------
// 512 thr = 8 waves/block; W1 staged to LDS (fp32, 64 KB) once; one wave per node,
// lane l owns channels {l, l+64}: two stride-1 ds_read_b32 per k (conflict-free).
__global__ __launch_bounds__(512) void k1_gemm1(const void* __restrict__ x,
                                                const void* __restrict__ W1,
                                                const void* __restrict__ a_s,
                                                const void* __restrict__ a_d,
                                                const int* __restrict__ flags,
                                                __hip_bfloat16* __restrict__ h1,
                                                float* __restrict__ al_s,
                                                float* __restrict__ al_d, int N) {
    __shared__ float W1s[128 * 128];   // 64 KB
    int t = threadIdx.x;
    int fF = flags[0];
    if (fF) {
        #pragma unroll
        for (int i = 0; i < 8; ++i)
            ((float4*)W1s)[t + i * 512] = ((const float4*)W1)[t + i * 512];
    } else {
        #pragma unroll
        for (int i = 0; i < 32; ++i)
            W1s[t + i * 512] = bf2f(((const __hip_bfloat16*)W1)[t + i * 512]);
    }
    __syncthreads();
    int l = t & 63;
    float as0 = ldIn(a_s, l, fF), as1 = ldIn(a_s, 64 + l, fF);
    float ad0 = ldIn(a_d, l, fF), ad1 = ldIn(a_d, 64 + l, fF);
    int gw = blockIdx.x * 8 + (t >> 6);
    int stride = gridDim.x * 8;
    for (int n = gw; n < N; n += stride) {
        float2 xr;
        if (fF) {
            xr = ((const float2*)x)[(size_t)n * 64 + l];
        } else {
            __hip_bfloat162 p = ((const __hip_bfloat162*)x)[(size_t)n * 64 + l];
            xr.x = bf2f(p.x); xr.y = bf2f(p.y);
        }
        float a0 = 0.f, a1 = 0.f;
        #pragma unroll
        for (int k = 0; k < 128; ++k) {
            float xv = __shfl((k & 1) ? xr.y : xr.x, k >> 1, 64);
            a0 = fmaf(xv, W1s[k * 128 + l], a0);
            a1 = fmaf(xv, W1s[k * 128 + 64 + l], a1);
        }
        h1[(size_t)n * 128 + l]      = __float2bfloat16(a0);
        h1[(size_t)n * 128 + 64 + l] = __float2bfloat16(a1);
        // heads: chan l -> head l>>5 (0/1); chan l+64 -> head 2+(l>>5) (2/3)
        float p0 = a0 * as0, p1 = a1 * as1;
        float q0 = a0 * ad0, q1 = a1 * ad1;
        #pragma unroll
        for (int o = 16; o > 0; o >>= 1) {
            p0 += __shfl_down(p0, o, 32); p1 += __shfl_down(p1, o, 32);
            q0 += __shfl_down(q0, o, 32); q1 += __shfl_down(q1, o, 32);
        }
        if ((l & 31) == 0) {
            int hh = l >> 5;
            al_s[n * 4 + hh]     = p0;
            al_s[n * 4 + 2 + hh] = p1;
            al_d[n * 4 + hh]     = q0;
            al_d[n * 4 + 2 + hh] = q1;
        }
    }
}

// ---------------- fused layer-1 aggregation + ELU + GEMM2 + layer-2 logits ----------------
// block 128 = 2 waves; wave w handles dst d; lane owns bf162 channel pair (4 B/lane gathers).
__global__ void k2_fused1(const int* __restrict__ off, const int* __restrict__ srcs,
                          const __hip_bfloat16* __restrict__ h1,
                          const float* __restrict__ al_s, const float* __restrict__ al_d,
                          const void* __restrict__ b1, const void* __restrict__ W2,
                          const void* __restrict__ a_s2, const void* __restrict__ a_d2,
                          const int* __restrict__ flags,
                          __hip_bfloat16* __restrict__ h2,
                          float* __restrict__ al_s2, float* __restrict__ al_d2, int N) {
    int w = threadIdx.x >> 6, l = threadIdx.x & 63;
    int d = blockIdx.x * 2 + w;
    bool active = d < N;
    int fF = flags[0];
    __shared__ float tl[2][128];
    int h = l >> 4;                       // head of channels 2l, 2l+1
    float acc0 = 0.f, acc1 = 0.f, ssum = 0.f;
    if (active) {
        float ald = al_d[d * 4 + h];
        int j0 = off[d], j1 = off[d + 1];
        for (int j = j0; j < j1; ++j) {
            int src = srcs[j];
            float v = al_s[src * 4 + h] + ald;
            v = v >= 0.f ? v : NEG_SLOPE * v;
            float e = __expf(fminf(v, 30.f));
            ssum += e;
            __hip_bfloat162 hv = ((const __hip_bfloat162*)h1)[(size_t)src * 64 + l];
            acc0 = fmaf(e, bf2f(hv.x), acc0);
            acc1 = fmaf(e, bf2f(hv.y), acc1);
        }
        float r = 1.f / (ssum + 1e-16f);
        float o0 = acc0 * r + ldIn(b1, 2 * l, fF);
        float o1 = acc1 * r + ldIn(b1, 2 * l + 1, fF);
        o0 = o0 > 0.f ? o0 : (__expf(o0) - 1.f);
        o1 = o1 > 0.f ? o1 : (__expf(o1) - 1.f);
        tl[w][2 * l]     = o0;
        tl[w][2 * l + 1] = o1;
    }
    __syncthreads();
    if (active) {
        float a2 = 0.f;
        #pragma unroll 8
        for (int k = 0; k < 128; ++k)
            a2 = fmaf(tl[w][k], ldIn(W2, (size_t)k * 64 + l, fF), a2);
        h2[(size_t)d * 64 + l] = __float2bfloat16(a2);
        float ps = a2 * ldIn(a_s2, l, fF);
        float pd = a2 * ldIn(a_d2, l, fF);
        #pragma unroll
        for (int o = 32; o > 0; o >>= 1) {
            ps += __shfl_down(ps, o, 64);
            pd += __shfl_down(pd, o, 64);
        }
        if (l == 0) { al_s2[d] = ps; al_d2[d] = pd; }
    }
}

// ---------------- fused layer-2 aggregation + bias -> fp32 output ----------------
__global__ void k3_fused2(const int* __restrict__ off, const int* __restrict__ srcs,
                          const __hip_bfloat16* __restrict__ h2,
                          const float* __restrict__ al_s2, const float* __restrict__ al_d2,
                          const void* __restrict__ b2, const int* __restrict__ flags,
                          float* __restrict__ out, int N) {
    int w = threadIdx.x >> 6, l = threadIdx.x & 63;
    int d = blockIdx.x * 2 + w;
    if (d >= N) return;                    // no barriers below: safe
    int fF = flags[0];
    float ald = al_d2[d];
    int j0 = off[d], j1 = off[d + 1];
    float acc = 0.f, ssum = 0.f;
    for (int j = j0; j < j1; ++j) {
        int src = srcs[j];
        float v = al_s2[src] + ald;
        v = v >= 0.f ? v : NEG_SLOPE * v;
        float e = __expf(fminf(v, 30.f));
        ssum += e;
        acc = fmaf(e, bf2f(h2[(size_t)src * 64 + l]), acc);
    }
    out[(size_t)d * 64 + l] = acc / (ssum + 1e-16f) + ldIn(b2, l, fF);
}

// diagnostic: ws too small -> broadcast ws_size (MB)
__global__ void k_report(float* out, int total, float code) {
    int i = blockIdx.x * 256 + threadIdx.x;
    if (i < total) out[i] = code;
}

extern "C" void kernel_launch(void* const* d_in, const int* in_sizes, int n_in,
                              void* d_out, int out_size, void* d_ws, size_t ws_size,
                              hipStream_t stream) {
    const void* x    = d_in[0];
    const int*  ei   = (const int*)d_in[1];
    const void* W1   = d_in[2];
    const void* a_s1 = d_in[3];
    const void* a_d1 = d_in[4];
    const void* b1   = d_in[5];
    const void* W2   = d_in[6];
    const void* a_s2 = d_in[7];
    const void* a_d2 = d_in[8];
    const void* b2   = d_in[9];
    const int N = in_sizes[0] / IN_C;
    const int E = in_sizes[1] / 2;
    const int NB = (N + 2047) / 2048;      // scan chunks (<=256 supported)

    char* p = (char*)d_ws;
    int* flags   = (int*)p;                 p += 256;
    int* csr_off = (int*)p;                 p += ((size_t)(N + 1) * 4 + 255) / 256 * 256;
    int* csr_pos = (int*)p;                 p += ((size_t)N * 4 + 255) / 256 * 256;
    int* csr_src = (int*)p;                 p += ((size_t)E * 4 + 255) / 256 * 256;
    int* bsum    = (int*)p;                 p += 1024;
    int* bbase   = (int*)p;                 p += 1024;
    float* al_s1 = (float*)p;               p += (size_t)N * 4 * 4;
    float* al_d1 = (float*)p;               p += (size_t)N * 4 * 4;
    float* al_s2 = (float*)p;               p += (size_t)N * 4;
    float* al_d2 = (float*)p;               p += (size_t)N * 4;
    __hip_bfloat16* h1 = (__hip_bfloat16*)p; p += (size_t)N * 128 * 2;
    __hip_bfloat16* h2 = (__hip_bfloat16*)p; p += (size_t)N * 64 * 2;
    size_t needed = (size_t)(p - (char*)d_ws);

    if (ws_size < needed) {
        k_report<<<(out_size + 255) / 256, 256, 0, stream>>>(
            (float*)d_out, out_size, (float)(ws_size >> 20));
        return;
    }

    hipMemsetAsync(flags, 0, 256, stream);
    hipMemsetAsync(csr_pos, 0, (size_t)N * 4, stream);

    k0_probe<<<1, 512, 0, stream>>>(x, ei, flags);
    k_count<<<(E + 255) / 256, 256, 0, stream>>>(ei, flags, csr_pos, E, N);
    k_scanA<<<NB, 256, 0, stream>>>(csr_pos, bsum, N);
    k_scanB<<<1, 256, 0, stream>>>(bsum, bbase, csr_off, NB, N);
    k_scanC<<<NB, 256, 0, stream>>>(csr_pos, csr_off, bbase, N);
    k_fill<<<(E + 255) / 256, 256, 0, stream>>>(ei, flags, csr_pos, csr_src, E, N);

    k1_gemm1<<<512, 512, 0, stream>>>(x, W1, a_s1, a_d1, flags, h1, al_s1, al_d1, N);
    k2_fused1<<<(N + 1) / 2, 128, 0, stream>>>(csr_off, csr_src, h1, al_s1, al_d1,
                                               b1, W2, a_s2, a_d2, flags, h2, al_s2, al_d2, N);
    k3_fused2<<<(N + 1) / 2, 128, 0, stream>>>(csr_off, csr_src, h2, al_s2, al_d2, b2, flags,
                                               (float*)d_out, N);
}

// Round 6
// 741.143 us; speedup vs baseline: 2.2013x; 2.1010x over previous
//
#include <hip/hip_runtime.h>
#include <hip/hip_bf16.h>

#define IN_C 128
#define HEADS 4
#define HID 32
#define OUT_C 64
#define NEG_SLOPE 0.2f

typedef short bf16x8 __attribute__((ext_vector_type(8)));
typedef float f32x4 __attribute__((ext_vector_type(4)));

static __device__ __forceinline__ float bf2f(__hip_bfloat16 b) { return __bfloat162float(b); }

static __device__ __forceinline__ short f2bf_s(float f) {
    __hip_bfloat16 h = __float2bfloat16(f);
    return *reinterpret_cast<short*>(&h);
}

static __device__ __forceinline__ int clampIdx(int i, int n) {
    return ((unsigned)i < (unsigned)n) ? i : 0;
}

// Dual-path input load: fp32 (confirmed round 4) or bf16.
static __device__ __forceinline__ float ldIn(const void* p, size_t i, int isF) {
    return isF ? ((const float*)p)[i] : bf2f(((const __hip_bfloat16*)p)[i]);
}

static __device__ __forceinline__ int ldSrc(const int* ei, int e, int E, int i64) {
    return i64 ? ei[2 * e] : ei[e];
}
static __device__ __forceinline__ int ldDst(const int* ei, int e, int E, int i64) {
    return i64 ? ei[2 * (E + e)] : ei[E + e];
}

static __device__ __forceinline__ int scan256_incl(int v, int t) {
    for (int o = 1; o < 64; o <<= 1) {
        int u = __shfl_up(v, o, 64);
        if ((t & 63) >= o) v += u;
    }
    __shared__ int wsum[4];
    if ((t & 63) == 63) wsum[t >> 6] = v;
    __syncthreads();
    int base = 0;
    #pragma unroll
    for (int i = 0; i < 4; ++i) base += (i < (t >> 6)) ? wsum[i] : 0;
    __syncthreads();
    return base + v;
}

// ---------------- probes ----------------
__global__ void k0_probe(const void* x, const int* ei, int* flags) {
    int t = threadIdx.x;  // 512
    float v = bf2f(((const __hip_bfloat16*)x)[t]);
    if (!(fabsf(v) <= 1e10f)) atomicOr(&flags[0], 1);  // fp32 detected
    if (t < 256) {
        if (ei[2 * t + 1] != 0) atomicOr(&flags[1], 1); // int32 detected
    }
}

// ---------------- CSR build ----------------
__global__ void k_count(const int* __restrict__ ei, const int* __restrict__ flags,
                        int* __restrict__ cnt, int E, int N) {
    int e = blockIdx.x * 256 + threadIdx.x;
    if (e >= E) return;
    int i64 = (flags[1] == 0);
    atomicAdd(&cnt[clampIdx(ldDst(ei, e, E, i64), N)], 1);
}

__global__ void k_scanA(const int* __restrict__ cnt, int* __restrict__ bsum, int N) {
    int t = threadIdx.x, blk = blockIdx.x;
    int s = 0;
    #pragma unroll
    for (int j = 0; j < 8; ++j) {
        int idx = blk * 2048 + j * 256 + t;
        s += (idx < N) ? cnt[idx] : 0;
    }
    #pragma unroll
    for (int o = 32; o > 0; o >>= 1) s += __shfl_down(s, o, 64);
    __shared__ int ws4[4];
    if ((t & 63) == 0) ws4[t >> 6] = s;
    __syncthreads();
    if (t == 0) bsum[blk] = ws4[0] + ws4[1] + ws4[2] + ws4[3];
}

__global__ void k_scanB(const int* __restrict__ bsum, int* __restrict__ bbase,
                        int* __restrict__ off, int NB, int N) {
    int t = threadIdx.x;
    int v = (t < NB) ? bsum[t] : 0;
    int incl = scan256_incl(v, t);
    if (t < NB) bbase[t] = incl - v;
    if (t == 255) off[N] = incl;
}

__global__ void k_scanC(int* __restrict__ cnt_pos, int* __restrict__ off,
                        const int* __restrict__ bbase, int N) {
    int t = threadIdx.x, blk = blockIdx.x;
    int base_i = blk * 2048 + t * 8;
    int c[8], pre[8];
    #pragma unroll
    for (int j = 0; j < 8; ++j) c[j] = (base_i + j < N) ? cnt_pos[base_i + j] : 0;
    int s = 0;
    #pragma unroll
    for (int j = 0; j < 8; ++j) { pre[j] = s; s += c[j]; }
    int incl = scan256_incl(s, t);
    int gexcl = bbase[blk] + incl - s;
    #pragma unroll
    for (int j = 0; j < 8; ++j) {
        int i = base_i + j;
        if (i < N) {
            int v = gexcl + pre[j];
            off[i] = v;
            cnt_pos[i] = v;
        }
    }
}

__global__ void k_fill(const int* __restrict__ ei, const int* __restrict__ flags,
                       int* __restrict__ pos, int* __restrict__ srcs, int E, int N) {
    int e = blockIdx.x * 256 + threadIdx.x;
    if (e >= E) return;
    int i64 = (flags[1] == 0);
    int src = clampIdx(ldSrc(ei, e, E, i64), N);
    int dst = clampIdx(ldDst(ei, e, E, i64), N);
    int p = atomicAdd(&pos[dst], 1);
    if (p >= 0 && p < E) srcs[p] = src;
}

// ---------------- W1 transpose+convert: w1t[n][k] = bf16(W1[k][n]) ----------------
__global__ void kw1t(const void* __restrict__ W1, const int* __restrict__ flags,
                     short* __restrict__ w1t) {
    int t = blockIdx.x * 256 + threadIdx.x;  // 16384
    if (t >= 128 * 128) return;
    int n = t >> 7, k = t & 127;
    w1t[t] = f2bf_s(ldIn(W1, (size_t)k * 128 + n, flags[0]));
}

// ---------------- layer 1 GEMM via MFMA: h1[N,128] bf16 = x @ W1 ----------------
// block = 256 thr (4 waves) computes 64 rows x 128 cols. K=128 staged entirely in LDS.
// LDS rows padded to 136 bf16 (272 B = 68 dw stride -> only 2-way bank aliasing, free).
__global__ __launch_bounds__(256) void k1_mfma(const void* __restrict__ x,
                                               const short* __restrict__ w1t,
                                               const int* __restrict__ flags,
                                               __hip_bfloat16* __restrict__ h1, int N) {
    __shared__ short xs[64][136];    // 17.0 KB
    __shared__ short ws[128][136];   // 34.0 KB
    int t = threadIdx.x;
    int R = blockIdx.x * 64;
    int fF = flags[0];
    // stage W1T (bf16, contiguous): 2048 chunks of 16 B
    #pragma unroll
    for (int i = 0; i < 8; ++i) {
        int chunk = t + i * 256;
        int n = chunk >> 4, cc = chunk & 15;
        *(bf16x8*)&ws[n][cc * 8] = ((const bf16x8*)w1t)[chunk];
    }
    // stage x tile with on-the-fly fp32->bf16: 1024 chunks of 8 elems
    #pragma unroll
    for (int i = 0; i < 4; ++i) {
        int chunk = t + i * 256;
        int row = chunk >> 4, cc = chunk & 15;
        bf16x8 v;
        if (R + row < N) {
            if (fF) {
                const float4* xg = (const float4*)x;
                float4 fa = xg[(size_t)(R + row) * 32 + cc * 2];
                float4 fb = xg[(size_t)(R + row) * 32 + cc * 2 + 1];
                v[0] = f2bf_s(fa.x); v[1] = f2bf_s(fa.y);
                v[2] = f2bf_s(fa.z); v[3] = f2bf_s(fa.w);
                v[4] = f2bf_s(fb.x); v[5] = f2bf_s(fb.y);
                v[6] = f2bf_s(fb.z); v[7] = f2bf_s(fb.w);
            } else {
                v = ((const bf16x8*)x)[(size_t)(R + row) * 16 + cc];
            }
        } else {
            #pragma unroll
            for (int j = 0; j < 8; ++j) v[j] = 0;
        }
        *(bf16x8*)&xs[row][cc * 8] = v;
    }
    __syncthreads();
    int lane = t & 63, w = t >> 6;
    int q = lane >> 4, m = lane & 15;
    f32x4 acc[8];
    #pragma unroll
    for (int c = 0; c < 8; ++c)
        #pragma unroll
        for (int r = 0; r < 4; ++r) acc[c][r] = 0.f;
    // A-frag: row m=lane&15, k=q*8+j  (m120-verified A layout)
    // B-frag: col n=lane&15, k=q*8+j  -> read W1T[n][k]
    #pragma unroll
    for (int ks = 0; ks < 4; ++ks) {
        bf16x8 a = *(const bf16x8*)&xs[16 * w + m][ks * 32 + q * 8];
        #pragma unroll
        for (int c = 0; c < 8; ++c) {
            bf16x8 b = *(const bf16x8*)&ws[16 * c + m][ks * 32 + q * 8];
            acc[c] = __builtin_amdgcn_mfma_f32_16x16x32_bf16(a, b, acc[c], 0, 0, 0);
        }
    }
    // C/D: col=lane&15, row=q*4+reg (m89-verified)
    #pragma unroll
    for (int c = 0; c < 8; ++c)
        #pragma unroll
        for (int r = 0; r < 4; ++r) {
            int grow = R + 16 * w + q * 4 + r;
            if (grow < N)
                h1[(size_t)grow * 128 + 16 * c + m] = __float2bfloat16(acc[c][r]);
        }
}

// ---------------- layer-1 logits from h1 ----------------
__global__ void k1b_logits(const __hip_bfloat16* __restrict__ h1,
                           const void* __restrict__ a_s, const void* __restrict__ a_d,
                           const int* __restrict__ flags,
                           float* __restrict__ al_s, float* __restrict__ al_d, int N) {
    int t = threadIdx.x;
    int l = t & 63;
    int n = blockIdx.x * 4 + (t >> 6);
    if (n >= N) return;
    int fF = flags[0];
    __hip_bfloat162 hv = ((const __hip_bfloat162*)h1)[(size_t)n * 64 + l];
    float v0 = bf2f(hv.x), v1 = bf2f(hv.y);
    float ps = v0 * ldIn(a_s, 2 * l, fF) + v1 * ldIn(a_s, 2 * l + 1, fF);
    float pd = v0 * ldIn(a_d, 2 * l, fF) + v1 * ldIn(a_d, 2 * l + 1, fF);
    #pragma unroll
    for (int o = 8; o > 0; o >>= 1) {
        ps += __shfl_down(ps, o, 16);
        pd += __shfl_down(pd, o, 16);
    }
    if ((l & 15) == 0) {
        al_s[n * 4 + (l >> 4)] = ps;
        al_d[n * 4 + (l >> 4)] = pd;
    }
}

// ---------------- fused layer-1 aggregation + ELU + GEMM2 + layer-2 logits ----------------
__global__ void k2_fused1(const int* __restrict__ off, const int* __restrict__ srcs,
                          const __hip_bfloat16* __restrict__ h1,
                          const float* __restrict__ al_s, const float* __restrict__ al_d,
                          const void* __restrict__ b1, const void* __restrict__ W2,
                          const void* __restrict__ a_s2, const void* __restrict__ a_d2,
                          const int* __restrict__ flags,
                          __hip_bfloat16* __restrict__ h2,
                          float* __restrict__ al_s2, float* __restrict__ al_d2, int N) {
    int w = threadIdx.x >> 6, l = threadIdx.x & 63;
    int d = blockIdx.x * 2 + w;
    bool active = d < N;
    int fF = flags[0];
    __shared__ float tl[2][128];
    int h = l >> 4;
    float acc0 = 0.f, acc1 = 0.f, ssum = 0.f;
    if (active) {
        float ald = al_d[d * 4 + h];
        int j0 = off[d], j1 = off[d + 1];
        for (int j = j0; j < j1; ++j) {
            int src = srcs[j];
            float v = al_s[src * 4 + h] + ald;
            v = v >= 0.f ? v : NEG_SLOPE * v;
            float e = __expf(fminf(v, 30.f));
            ssum += e;
            __hip_bfloat162 hv = ((const __hip_bfloat162*)h1)[(size_t)src * 64 + l];
            acc0 = fmaf(e, bf2f(hv.x), acc0);
            acc1 = fmaf(e, bf2f(hv.y), acc1);
        }
        float r = 1.f / (ssum + 1e-16f);
        float o0 = acc0 * r + ldIn(b1, 2 * l, fF);
        float o1 = acc1 * r + ldIn(b1, 2 * l + 1, fF);
        o0 = o0 > 0.f ? o0 : (__expf(o0) - 1.f);
        o1 = o1 > 0.f ? o1 : (__expf(o1) - 1.f);
        tl[w][2 * l]     = o0;
        tl[w][2 * l + 1] = o1;
    }
    __syncthreads();
    if (active) {
        float a2 = 0.f;
        #pragma unroll 8
        for (int k = 0; k < 128; ++k)
            a2 = fmaf(tl[w][k], ldIn(W2, (size_t)k * 64 + l, fF), a2);
        h2[(size_t)d * 64 + l] = __float2bfloat16(a2);
        float ps = a2 * ldIn(a_s2, l, fF);
        float pd = a2 * ldIn(a_d2, l, fF);
        #pragma unroll
        for (int o = 32; o > 0; o >>= 1) {
            ps += __shfl_down(ps, o, 64);
            pd += __shfl_down(pd, o, 64);
        }
        if (l == 0) { al_s2[d] = ps; al_d2[d] = pd; }
    }
}

// ---------------- fused layer-2 aggregation + bias -> fp32 output ----------------
__global__ void k3_fused2(const int* __restrict__ off, const int* __restrict__ srcs,
                          const __hip_bfloat16* __restrict__ h2,
                          const float* __restrict__ al_s2, const float* __restrict__ al_d2,
                          const void* __restrict__ b2, const int* __restrict__ flags,
                          float* __restrict__ out, int N) {
    int w = threadIdx.x >> 6, l = threadIdx.x & 63;
    int d = blockIdx.x * 2 + w;
    if (d >= N) return;
    int fF = flags[0];
    float ald = al_d2[d];
    int j0 = off[d], j1 = off[d + 1];
    float acc = 0.f, ssum = 0.f;
    for (int j = j0; j < j1; ++j) {
        int src = srcs[j];
        float v = al_s2[src] + ald;
        v = v >= 0.f ? v : NEG_SLOPE * v;
        float e = __expf(fminf(v, 30.f));
        ssum += e;
        acc = fmaf(e, bf2f(h2[(size_t)src * 64 + l]), acc);
    }
    out[(size_t)d * 64 + l] = acc / (ssum + 1e-16f) + ldIn(b2, l, fF);
}

__global__ void k_report(float* out, int total, float code) {
    int i = blockIdx.x * 256 + threadIdx.x;
    if (i < total) out[i] = code;
}

extern "C" void kernel_launch(void* const* d_in, const int* in_sizes, int n_in,
                              void* d_out, int out_size, void* d_ws, size_t ws_size,
                              hipStream_t stream) {
    const void* x    = d_in[0];
    const int*  ei   = (const int*)d_in[1];
    const void* W1   = d_in[2];
    const void* a_s1 = d_in[3];
    const void* a_d1 = d_in[4];
    const void* b1   = d_in[5];
    const void* W2   = d_in[6];
    const void* a_s2 = d_in[7];
    const void* a_d2 = d_in[8];
    const void* b2   = d_in[9];
    const int N = in_sizes[0] / IN_C;
    const int E = in_sizes[1] / 2;
    const int NB = (N + 2047) / 2048;

    char* p = (char*)d_ws;
    int* flags   = (int*)p;                 p += 256;
    int* csr_off = (int*)p;                 p += ((size_t)(N + 1) * 4 + 255) / 256 * 256;
    int* csr_pos = (int*)p;                 p += ((size_t)N * 4 + 255) / 256 * 256;
    int* csr_src = (int*)p;                 p += ((size_t)E * 4 + 255) / 256 * 256;
    int* bsum    = (int*)p;                 p += 1024;
    int* bbase   = (int*)p;                 p += 1024;
    short* w1t   = (short*)p;               p += 128 * 128 * 2;          // 32 KB
    float* al_s1 = (float*)p;               p += (size_t)N * 4 * 4;
    float* al_d1 = (float*)p;               p += (size_t)N * 4 * 4;
    float* al_s2 = (float*)p;               p += (size_t)N * 4;
    float* al_d2 = (float*)p;               p += (size_t)N * 4;
    __hip_bfloat16* h1 = (__hip_bfloat16*)p; p += (size_t)N * 128 * 2;
    __hip_bfloat16* h2 = (__hip_bfloat16*)p; p += (size_t)N * 64 * 2;
    size_t needed = (size_t)(p - (char*)d_ws);

    if (ws_size < needed) {
        k_report<<<(out_size + 255) / 256, 256, 0, stream>>>(
            (float*)d_out, out_size, (float)(ws_size >> 20));
        return;
    }

    hipMemsetAsync(flags, 0, 256, stream);
    hipMemsetAsync(csr_pos, 0, (size_t)N * 4, stream);

    k0_probe<<<1, 512, 0, stream>>>(x, ei, flags);
    kw1t<<<64, 256, 0, stream>>>(W1, flags, w1t);
    k_count<<<(E + 255) / 256, 256, 0, stream>>>(ei, flags, csr_pos, E, N);
    k_scanA<<<NB, 256, 0, stream>>>(csr_pos, bsum, N);
    k_scanB<<<1, 256, 0, stream>>>(bsum, bbase, csr_off, NB, N);
    k_scanC<<<NB, 256, 0, stream>>>(csr_pos, csr_off, bbase, N);
    k_fill<<<(E + 255) / 256, 256, 0, stream>>>(ei, flags, csr_pos, csr_src, E, N);

    k1_mfma<<<(N + 63) / 64, 256, 0, stream>>>(x, w1t, flags, h1, N);
    k1b_logits<<<(N + 3) / 4, 256, 0, stream>>>(h1, a_s1, a_d1, flags, al_s1, al_d1, N);
    k2_fused1<<<(N + 1) / 2, 128, 0, stream>>>(csr_off, csr_src, h1, al_s1, al_d1,
                                               b1, W2, a_s2, a_d2, flags, h2, al_s2, al_d2, N);
    k3_fused2<<<(N + 1) / 2, 128, 0, stream>>>(csr_off, csr_src, h2, al_s2, al_d2, b2, flags,
                                               (float*)d_out, N);
}

// Round 8
// 526.827 us; speedup vs baseline: 3.0968x; 1.4068x over previous
//
#include <hip/hip_runtime.h>
#include <hip/hip_bf16.h>

#define IN_C 128
#define HEADS 4
#define HID 32
#define OUT_C 64
#define NEG_SLOPE 0.2f

typedef short bf16x8 __attribute__((ext_vector_type(8)));
typedef float f32x4 __attribute__((ext_vector_type(4)));

static __device__ __forceinline__ float bf2f(__hip_bfloat16 b) { return __bfloat162float(b); }

static __device__ __forceinline__ short f2bf_s(float f) {
    __hip_bfloat16 h = __float2bfloat16(f);
    return *reinterpret_cast<short*>(&h);
}

static __device__ __forceinline__ float bss2f(short s) {
    union { int i; float f; } u;
    u.i = ((int)s) << 16;
    return u.f;
}

static __device__ __forceinline__ int clampIdx(int i, int n) {
    return ((unsigned)i < (unsigned)n) ? i : 0;
}

// Dual-path input load: fp32 (confirmed round 4) or bf16.
static __device__ __forceinline__ float ldIn(const void* p, size_t i, int isF) {
    return isF ? ((const float*)p)[i] : bf2f(((const __hip_bfloat16*)p)[i]);
}

static __device__ __forceinline__ int ldSrc(const int* ei, int e, int E, int i64) {
    return i64 ? ei[2 * e] : ei[e];
}
static __device__ __forceinline__ int ldDst(const int* ei, int e, int E, int i64) {
    return i64 ? ei[2 * (E + e)] : ei[E + e];
}

static __device__ __forceinline__ int scan256_incl(int v, int t) {
    for (int o = 1; o < 64; o <<= 1) {
        int u = __shfl_up(v, o, 64);
        if ((t & 63) >= o) v += u;
    }
    __shared__ int wsum[4];
    if ((t & 63) == 63) wsum[t >> 6] = v;
    __syncthreads();
    int base = 0;
    #pragma unroll
    for (int i = 0; i < 4; ++i) base += (i < (t >> 6)) ? wsum[i] : 0;
    __syncthreads();
    return base + v;
}

// ---------------- probes ----------------
__global__ void k0_probe(const void* x, const int* ei, int* flags) {
    int t = threadIdx.x;  // 512
    float v = bf2f(((const __hip_bfloat16*)x)[t]);
    if (!(fabsf(v) <= 1e10f)) atomicOr(&flags[0], 1);  // fp32 detected
    if (t < 256) {
        if (ei[2 * t + 1] != 0) atomicOr(&flags[1], 1); // int32 detected
    }
}

// ---------------- CSR build ----------------
__global__ void k_count(const int* __restrict__ ei, const int* __restrict__ flags,
                        int* __restrict__ cnt, int E, int N) {
    int e = blockIdx.x * 256 + threadIdx.x;
    if (e >= E) return;
    int i64 = (flags[1] == 0);
    atomicAdd(&cnt[clampIdx(ldDst(ei, e, E, i64), N)], 1);
}

__global__ void k_scanA(const int* __restrict__ cnt, int* __restrict__ bsum, int N) {
    int t = threadIdx.x, blk = blockIdx.x;
    int s = 0;
    #pragma unroll
    for (int j = 0; j < 8; ++j) {
        int idx = blk * 2048 + j * 256 + t;
        s += (idx < N) ? cnt[idx] : 0;
    }
    #pragma unroll
    for (int o = 32; o > 0; o >>= 1) s += __shfl_down(s, o, 64);
    __shared__ int ws4[4];
    if ((t & 63) == 0) ws4[t >> 6] = s;
    __syncthreads();
    if (t == 0) bsum[blk] = ws4[0] + ws4[1] + ws4[2] + ws4[3];
}

__global__ void k_scanB(const int* __restrict__ bsum, int* __restrict__ bbase,
                        int* __restrict__ off, int NB, int N) {
    int t = threadIdx.x;
    int v = (t < NB) ? bsum[t] : 0;
    int incl = scan256_incl(v, t);
    if (t < NB) bbase[t] = incl - v;
    if (t == 255) off[N] = incl;
}

__global__ void k_scanC(int* __restrict__ cnt_pos, int* __restrict__ off,
                        const int* __restrict__ bbase, int N) {
    int t = threadIdx.x, blk = blockIdx.x;
    int base_i = blk * 2048 + t * 8;
    int c[8], pre[8];
    #pragma unroll
    for (int j = 0; j < 8; ++j) c[j] = (base_i + j < N) ? cnt_pos[base_i + j] : 0;
    int s = 0;
    #pragma unroll
    for (int j = 0; j < 8; ++j) { pre[j] = s; s += c[j]; }
    int incl = scan256_incl(s, t);
    int gexcl = bbase[blk] + incl - s;
    #pragma unroll
    for (int j = 0; j < 8; ++j) {
        int i = base_i + j;
        if (i < N) {
            int v = gexcl + pre[j];
            off[i] = v;
            cnt_pos[i] = v;
        }
    }
}

__global__ void k_fill(const int* __restrict__ ei, const int* __restrict__ flags,
                       int* __restrict__ pos, int* __restrict__ srcs, int E, int N) {
    int e = blockIdx.x * 256 + threadIdx.x;
    if (e >= E) return;
    int i64 = (flags[1] == 0);
    int src = clampIdx(ldSrc(ei, e, E, i64), N);
    int dst = clampIdx(ldDst(ei, e, E, i64), N);
    int p = atomicAdd(&pos[dst], 1);
    if (p >= 0 && p < E) srcs[p] = src;
}

// ---------------- weight transpose+convert ----------------
__global__ void kw1t(const void* __restrict__ W1, const int* __restrict__ flags,
                     short* __restrict__ w1t) {
    int t = blockIdx.x * 256 + threadIdx.x;  // 16384
    if (t >= 128 * 128) return;
    int n = t >> 7, k = t & 127;
    w1t[t] = f2bf_s(ldIn(W1, (size_t)k * 128 + n, flags[0]));
}

__global__ void kw2t(const void* __restrict__ W2, const int* __restrict__ flags,
                     short* __restrict__ w2t) {
    int t = blockIdx.x * 256 + threadIdx.x;  // 8192
    if (t >= 64 * 128) return;
    int n = t >> 7, k = t & 127;
    w2t[t] = f2bf_s(ldIn(W2, (size_t)k * 64 + n, flags[0]));
}

// ---------------- layer 1 GEMM via MFMA: h1[N,128] bf16 = x @ W1 ----------------
__global__ __launch_bounds__(256) void k1_mfma(const void* __restrict__ x,
                                               const short* __restrict__ w1t,
                                               const int* __restrict__ flags,
                                               __hip_bfloat16* __restrict__ h1, int N) {
    __shared__ short xs[64][136];
    __shared__ short ws[128][136];
    int t = threadIdx.x;
    int R = blockIdx.x * 64;
    int fF = flags[0];
    #pragma unroll
    for (int i = 0; i < 8; ++i) {
        int chunk = t + i * 256;
        int n = chunk >> 4, cc = chunk & 15;
        *(bf16x8*)&ws[n][cc * 8] = ((const bf16x8*)w1t)[chunk];
    }
    #pragma unroll
    for (int i = 0; i < 4; ++i) {
        int chunk = t + i * 256;
        int row = chunk >> 4, cc = chunk & 15;
        bf16x8 v;
        if (R + row < N) {
            if (fF) {
                const float4* xg = (const float4*)x;
                float4 fa = xg[(size_t)(R + row) * 32 + cc * 2];
                float4 fb = xg[(size_t)(R + row) * 32 + cc * 2 + 1];
                v[0] = f2bf_s(fa.x); v[1] = f2bf_s(fa.y);
                v[2] = f2bf_s(fa.z); v[3] = f2bf_s(fa.w);
                v[4] = f2bf_s(fb.x); v[5] = f2bf_s(fb.y);
                v[6] = f2bf_s(fb.z); v[7] = f2bf_s(fb.w);
            } else {
                v = ((const bf16x8*)x)[(size_t)(R + row) * 16 + cc];
            }
        } else {
            #pragma unroll
            for (int j = 0; j < 8; ++j) v[j] = 0;
        }
        *(bf16x8*)&xs[row][cc * 8] = v;
    }
    __syncthreads();
    int lane = t & 63, w = t >> 6;
    int q = lane >> 4, m = lane & 15;
    f32x4 acc[8];
    #pragma unroll
    for (int c = 0; c < 8; ++c)
        #pragma unroll
        for (int r = 0; r < 4; ++r) acc[c][r] = 0.f;
    #pragma unroll
    for (int ks = 0; ks < 4; ++ks) {
        bf16x8 a = *(const bf16x8*)&xs[16 * w + m][ks * 32 + q * 8];
        #pragma unroll
        for (int c = 0; c < 8; ++c) {
            bf16x8 b = *(const bf16x8*)&ws[16 * c + m][ks * 32 + q * 8];
            acc[c] = __builtin_amdgcn_mfma_f32_16x16x32_bf16(a, b, acc[c], 0, 0, 0);
        }
    }
    #pragma unroll
    for (int c = 0; c < 8; ++c)
        #pragma unroll
        for (int r = 0; r < 4; ++r) {
            int grow = R + 16 * w + q * 4 + r;
            if (grow < N)
                h1[(size_t)grow * 128 + 16 * c + m] = __float2bfloat16(acc[c][r]);
        }
}

// ---------------- layer-1 logits from h1 ----------------
__global__ void k1b_logits(const __hip_bfloat16* __restrict__ h1,
                           const void* __restrict__ a_s, const void* __restrict__ a_d,
                           const int* __restrict__ flags,
                           float* __restrict__ al_s, float* __restrict__ al_d, int N) {
    int t = threadIdx.x;
    int l = t & 63;
    int n = blockIdx.x * 4 + (t >> 6);
    if (n >= N) return;
    int fF = flags[0];
    __hip_bfloat162 hv = ((const __hip_bfloat162*)h1)[(size_t)n * 64 + l];
    float v0 = bf2f(hv.x), v1 = bf2f(hv.y);
    float ps = v0 * ldIn(a_s, 2 * l, fF) + v1 * ldIn(a_s, 2 * l + 1, fF);
    float pd = v0 * ldIn(a_d, 2 * l, fF) + v1 * ldIn(a_d, 2 * l + 1, fF);
    #pragma unroll
    for (int o = 8; o > 0; o >>= 1) {
        ps += __shfl_down(ps, o, 16);
        pd += __shfl_down(pd, o, 16);
    }
    if ((l & 15) == 0) {
        al_s[n * 4 + (l >> 4)] = ps;
        al_d[n * 4 + (l >> 4)] = pd;
    }
}

// ---------------- fused layer-1 aggregation + ELU + MFMA GEMM2 + layer-2 logits ----------------
// block = 256 thr (4 waves) handles 16 dst rows.
// Edge phase: wave processes 4 edges/iter (16 lanes x bf16x8 = one 128-ch h1 row).
// GEMM2: A = tl[16][128] bf16 (LDS), B = W2T staged in LDS; wave w -> channel tile 16w.
__global__ __launch_bounds__(256) void k2_fused1(const int* __restrict__ off,
                                                 const int* __restrict__ srcs,
                                                 const __hip_bfloat16* __restrict__ h1,
                                                 const float* __restrict__ al_s,
                                                 const float* __restrict__ al_d,
                                                 const void* __restrict__ b1,
                                                 const short* __restrict__ w2t,
                                                 const void* __restrict__ a_s2,
                                                 const void* __restrict__ a_d2,
                                                 const int* __restrict__ flags,
                                                 __hip_bfloat16* __restrict__ h2,
                                                 float* __restrict__ al_s2,
                                                 float* __restrict__ al_d2, int N) {
    __shared__ short tl[16][136];
    __shared__ short ws2[64][136];
    __shared__ float pps[4][2][16];
    int t = threadIdx.x;
    int R = blockIdx.x * 16;
    int fF = flags[0];
    // stage W2T (bf16, 8192 elems = 1024 x 16B chunks)  [round-7 bug: was i<2 = half]
    #pragma unroll
    for (int i = 0; i < 4; ++i) {
        int chunk = t + i * 256;
        *(bf16x8*)&ws2[chunk >> 4][(chunk & 15) * 8] = ((const bf16x8*)w2t)[chunk];
    }
    int w = t >> 6, lane = t & 63;
    int li = lane & 15, g = lane >> 4;
    int h = li >> 2;   // head of channels [8li, 8li+8)
    #pragma unroll 1
    for (int i = 0; i < 4; ++i) {
        int dl = 4 * w + i;
        int d = R + dl;
        bool dok = d < N;
        int j0 = 0, j1 = 0;
        float ald = 0.f;
        if (dok) { j0 = off[d]; j1 = off[d + 1]; ald = al_d[d * 4 + h]; }
        float acc[8];
        #pragma unroll
        for (int c = 0; c < 8; ++c) acc[c] = 0.f;
        float ssum = 0.f;
        for (int j = j0; j < j1; j += 4) {
            int jj = j + g;
            bool ok = jj < j1;
            int src = srcs[ok ? jj : j];
            float v = al_s[src * 4 + h] + ald;
            v = v >= 0.f ? v : NEG_SLOPE * v;
            float e = ok ? __expf(fminf(v, 30.f)) : 0.f;
            ssum += e;
            bf16x8 hv = *(const bf16x8*)&h1[(size_t)src * 128 + li * 8];
            #pragma unroll
            for (int c = 0; c < 8; ++c) acc[c] = fmaf(e, bss2f(hv[c]), acc[c]);
        }
        ssum += __shfl_xor(ssum, 16);
        ssum += __shfl_xor(ssum, 32);
        #pragma unroll
        for (int c = 0; c < 8; ++c) {
            acc[c] += __shfl_xor(acc[c], 16);
            acc[c] += __shfl_xor(acc[c], 32);
        }
        if (g == 0) {
            float r = 1.f / (ssum + 1e-16f);
            bf16x8 tv;
            #pragma unroll
            for (int c = 0; c < 8; ++c) {
                float o = dok ? acc[c] * r + ldIn(b1, li * 8 + c, fF) : 0.f;
                o = o > 0.f ? o : (__expf(o) - 1.f);
                tv[c] = f2bf_s(o);
            }
            *(bf16x8*)&tl[dl][li * 8] = tv;
        }
    }
    __syncthreads();
    // GEMM2: wave w computes channels [16w, 16w+16) for all 16 dst rows
    int q = lane >> 4, m = lane & 15;
    f32x4 acc2 = {0.f, 0.f, 0.f, 0.f};
    #pragma unroll
    for (int ks = 0; ks < 4; ++ks) {
        bf16x8 a = *(const bf16x8*)&tl[m][ks * 32 + q * 8];
        bf16x8 b = *(const bf16x8*)&ws2[16 * w + m][ks * 32 + q * 8];
        acc2 = __builtin_amdgcn_mfma_f32_16x16x32_bf16(a, b, acc2, 0, 0, 0);
    }
    float as2v = ldIn(a_s2, 16 * w + m, fF);
    float ad2v = ldIn(a_d2, 16 * w + m, fF);
    float ps[4], pd[4];
    #pragma unroll
    for (int r = 0; r < 4; ++r) {
        int d = R + q * 4 + r;
        if (d < N) h2[(size_t)d * 64 + 16 * w + m] = __float2bfloat16(acc2[r]);
        ps[r] = acc2[r] * as2v;
        pd[r] = acc2[r] * ad2v;
    }
    #pragma unroll
    for (int o = 8; o > 0; o >>= 1) {
        #pragma unroll
        for (int r = 0; r < 4; ++r) {
            ps[r] += __shfl_down(ps[r], o, 16);
            pd[r] += __shfl_down(pd[r], o, 16);
        }
    }
    if (m == 0) {
        #pragma unroll
        for (int r = 0; r < 4; ++r) {
            pps[w][0][q * 4 + r] = ps[r];
            pps[w][1][q * 4 + r] = pd[r];
        }
    }
    __syncthreads();
    if (t < 32) {
        int row = t & 15, sd = t >> 4;
        float s = pps[0][sd][row] + pps[1][sd][row] + pps[2][sd][row] + pps[3][sd][row];
        int d = R + row;
        if (d < N) (sd ? al_d2 : al_s2)[d] = s;
    }
}

// ---------------- fused layer-2 aggregation + bias -> fp32 output ----------------
// block = 256 = 4 waves, one dst per wave; 8 edges/iter (8 lanes x bf16x8 per row).
__global__ __launch_bounds__(256) void k3_fused2(const int* __restrict__ off,
                                                 const int* __restrict__ srcs,
                                                 const __hip_bfloat16* __restrict__ h2,
                                                 const float* __restrict__ al_s2,
                                                 const float* __restrict__ al_d2,
                                                 const void* __restrict__ b2,
                                                 const int* __restrict__ flags,
                                                 float* __restrict__ out, int N) {
    int t = threadIdx.x;
    int w = t >> 6, lane = t & 63;
    int d = blockIdx.x * 4 + w;
    if (d >= N) return;
    int fF = flags[0];
    int li = lane & 7, g = lane >> 3;
    float ald = al_d2[d];
    int j0 = off[d], j1 = off[d + 1];
    float acc[8];
    #pragma unroll
    for (int c = 0; c < 8; ++c) acc[c] = 0.f;
    float ssum = 0.f;
    for (int j = j0; j < j1; j += 8) {
        int jj = j + g;
        bool ok = jj < j1;
        int src = srcs[ok ? jj : j];
        float v = al_s2[src] + ald;
        v = v >= 0.f ? v : NEG_SLOPE * v;
        float e = ok ? __expf(fminf(v, 30.f)) : 0.f;
        ssum += e;
        bf16x8 hv = *(const bf16x8*)&h2[(size_t)src * 64 + li * 8];
        #pragma unroll
        for (int c = 0; c < 8; ++c) acc[c] = fmaf(e, bss2f(hv[c]), acc[c]);
    }
    #pragma unroll
    for (int o = 8; o <= 32; o <<= 1) {
        ssum += __shfl_xor(ssum, o);
        #pragma unroll
        for (int c = 0; c < 8; ++c) acc[c] += __shfl_xor(acc[c], o);
    }
    if (g == 0) {
        float r = 1.f / (ssum + 1e-16f);
        float4 o0, o1;
        o0.x = acc[0] * r + ldIn(b2, li * 8 + 0, fF);
        o0.y = acc[1] * r + ldIn(b2, li * 8 + 1, fF);
        o0.z = acc[2] * r + ldIn(b2, li * 8 + 2, fF);
        o0.w = acc[3] * r + ldIn(b2, li * 8 + 3, fF);
        o1.x = acc[4] * r + ldIn(b2, li * 8 + 4, fF);
        o1.y = acc[5] * r + ldIn(b2, li * 8 + 5, fF);
        o1.z = acc[6] * r + ldIn(b2, li * 8 + 6, fF);
        o1.w = acc[7] * r + ldIn(b2, li * 8 + 7, fF);
        float4* op = (float4*)(out + (size_t)d * 64 + li * 8);
        op[0] = o0;
        op[1] = o1;
    }
}

__global__ void k_report(float* out, int total, float code) {
    int i = blockIdx.x * 256 + threadIdx.x;
    if (i < total) out[i] = code;
}

extern "C" void kernel_launch(void* const* d_in, const int* in_sizes, int n_in,
                              void* d_out, int out_size, void* d_ws, size_t ws_size,
                              hipStream_t stream) {
    const void* x    = d_in[0];
    const int*  ei   = (const int*)d_in[1];
    const void* W1   = d_in[2];
    const void* a_s1 = d_in[3];
    const void* a_d1 = d_in[4];
    const void* b1   = d_in[5];
    const void* W2   = d_in[6];
    const void* a_s2 = d_in[7];
    const void* a_d2 = d_in[8];
    const void* b2   = d_in[9];
    const int N = in_sizes[0] / IN_C;
    const int E = in_sizes[1] / 2;
    const int NB = (N + 2047) / 2048;

    char* p = (char*)d_ws;
    int* flags   = (int*)p;                 p += 256;
    int* csr_off = (int*)p;                 p += ((size_t)(N + 1) * 4 + 255) / 256 * 256;
    int* csr_pos = (int*)p;                 p += ((size_t)N * 4 + 255) / 256 * 256;
    int* csr_src = (int*)p;                 p += ((size_t)E * 4 + 255) / 256 * 256;
    int* bsum    = (int*)p;                 p += 1024;
    int* bbase   = (int*)p;                 p += 1024;
    short* w1t   = (short*)p;               p += 128 * 128 * 2;
    short* w2t   = (short*)p;               p += 64 * 128 * 2;
    float* al_s1 = (float*)p;               p += (size_t)N * 4 * 4;
    float* al_d1 = (float*)p;               p += (size_t)N * 4 * 4;
    float* al_s2 = (float*)p;               p += (size_t)N * 4;
    float* al_d2 = (float*)p;               p += (size_t)N * 4;
    __hip_bfloat16* h1 = (__hip_bfloat16*)p; p += (size_t)N * 128 * 2;
    __hip_bfloat16* h2 = (__hip_bfloat16*)p; p += (size_t)N * 64 * 2;
    size_t needed = (size_t)(p - (char*)d_ws);

    if (ws_size < needed) {
        k_report<<<(out_size + 255) / 256, 256, 0, stream>>>(
            (float*)d_out, out_size, (float)(ws_size >> 20));
        return;
    }

    hipMemsetAsync(flags, 0, 256, stream);
    hipMemsetAsync(csr_pos, 0, (size_t)N * 4, stream);

    k0_probe<<<1, 512, 0, stream>>>(x, ei, flags);
    kw1t<<<64, 256, 0, stream>>>(W1, flags, w1t);
    kw2t<<<32, 256, 0, stream>>>(W2, flags, w2t);
    k_count<<<(E + 255) / 256, 256, 0, stream>>>(ei, flags, csr_pos, E, N);
    k_scanA<<<NB, 256, 0, stream>>>(csr_pos, bsum, N);
    k_scanB<<<1, 256, 0, stream>>>(bsum, bbase, csr_off, NB, N);
    k_scanC<<<NB, 256, 0, stream>>>(csr_pos, csr_off, bbase, N);
    k_fill<<<(E + 255) / 256, 256, 0, stream>>>(ei, flags, csr_pos, csr_src, E, N);

    k1_mfma<<<(N + 63) / 64, 256, 0, stream>>>(x, w1t, flags, h1, N);
    k1b_logits<<<(N + 3) / 4, 256, 0, stream>>>(h1, a_s1, a_d1, flags, al_s1, al_d1, N);
    k2_fused1<<<(N + 15) / 16, 256, 0, stream>>>(csr_off, csr_src, h1, al_s1, al_d1,
                                                 b1, w2t, a_s2, a_d2, flags,
                                                 h2, al_s2, al_d2, N);
    k3_fused2<<<(N + 3) / 4, 256, 0, stream>>>(csr_off, csr_src, h2, al_s2, al_d2, b2, flags,
                                               (float*)d_out, N);
}